// Round 4
// baseline (142.593 us; speedup 1.0000x reference)
//
#include <hip/hip_runtime.h>
#include <hip/hip_bf16.h>

#define BB 4
#define CC 64
#define DD 8
#define NN 32768
#define WW 512
#define STR 256
#define NWIN 127
#define LOG2E 1.4426950408889634f

typedef short bf16x8 __attribute__((ext_vector_type(8)));
typedef float f32x4 __attribute__((ext_vector_type(4)));

__device__ __forceinline__ unsigned int pack_bf16(float lo, float hi) {
    __hip_bfloat162 h = __float22bfloat162_rn(make_float2(lo, hi));  // v_cvt_pk_bf16_f32
    unsigned int r; __builtin_memcpy(&r, &h, 4);
    return r;
}
__device__ __forceinline__ unsigned short to_bf16(float f) {
    __hip_bfloat16 h = __float2bfloat16(f);
    unsigned short r; __builtin_memcpy(&r, &h, 2);
    return r;
}
__device__ __forceinline__ float bf2f(unsigned short s) {
    union { unsigned int u; float f; } v; v.u = ((unsigned int)s) << 16;
    return v.f;
}

// ---------------- kernel 1: QKV projection (fp32 in, bf16 out) ----------------
// q,k layout: [b][n][8] bf16 (16B rows -> direct MFMA frag loads)
// v layout:   [b][c][n] bf16
// Wq/bq are pre-scaled by log2(e) so attention can use exp2 directly.
__global__ __launch_bounds__(256) void qkv_kernel(
    const float* __restrict__ x,
    const float* __restrict__ Wq, const float* __restrict__ bq,
    const float* __restrict__ Wk, const float* __restrict__ bk,
    const float* __restrict__ Wv, const float* __restrict__ bv,
    unsigned short* __restrict__ q, unsigned short* __restrict__ k,
    unsigned short* __restrict__ v)
{
    __shared__ float sWq[DD][CC], sWk[DD][CC], sWv[CC][CC];
    __shared__ float sb[2*DD + CC];
    const int t = threadIdx.x;
    for (int i = t; i < DD*CC; i += 256) { sWq[i>>6][i&63] = Wq[i] * LOG2E; sWk[i>>6][i&63] = Wk[i]; }
    for (int i = t; i < CC*CC; i += 256) sWv[i>>6][i&63] = Wv[i];
    if (t < DD) { sb[t] = bq[t] * LOG2E; sb[DD+t] = bk[t]; }
    if (t < CC) sb[2*DD+t] = bv[t];
    __syncthreads();

    const int gid = blockIdx.x*256 + t;
    const int b = gid >> 15;
    const int n = gid & (NN-1);
    const float* xb = x + (size_t)b*CC*NN + n;
    float xr[CC];
    #pragma unroll
    for (int c = 0; c < CC; ++c) xr[c] = xb[(size_t)c*NN];

    unsigned int pq[4], pk[4];
    #pragma unroll
    for (int d2 = 0; d2 < 4; ++d2) {
        float aq0 = sb[2*d2],   ak0 = sb[DD+2*d2];
        float aq1 = sb[2*d2+1], ak1 = sb[DD+2*d2+1];
        #pragma unroll
        for (int c = 0; c < CC; ++c) {
            aq0 = fmaf(sWq[2*d2][c],   xr[c], aq0);
            ak0 = fmaf(sWk[2*d2][c],   xr[c], ak0);
            aq1 = fmaf(sWq[2*d2+1][c], xr[c], aq1);
            ak1 = fmaf(sWk[2*d2+1][c], xr[c], ak1);
        }
        pq[d2] = pack_bf16(aq0, aq1);
        pk[d2] = pack_bf16(ak0, ak1);
    }
    *(int4*)(q + ((size_t)b*NN + n)*8) = make_int4(pq[0], pq[1], pq[2], pq[3]);
    *(int4*)(k + ((size_t)b*NN + n)*8) = make_int4(pk[0], pk[1], pk[2], pk[3]);

    unsigned short* vb = v + (size_t)b*CC*NN + n;
    for (int e = 0; e < CC; ++e) {
        float a = sb[2*DD+e];
        #pragma unroll
        for (int c = 0; c < CC; ++c) a = fmaf(sWv[e][c], xr[c], a);
        vb[(size_t)e*NN] = to_bf16(a);
    }
}

// ---------------- kernel 2: windowed attention, bf16 MFMA ----------------
// block = 4 waves; block owns (b, w, quarter-of-window-i = 128 rows).
// Each wave owns a 32-wide i-chunk, loops j in 32-tiles:
//   E^T = mfma(K_frag, Q_frag)  (K-dim = d, padded 8->32; Q zeroed for k>=8)
//   P = exp2(E^T) -> cvt_pk bf16 -> per-wave LDS tile [32i][40j]
//   acc += mfma(V_frag, P_frag); rowsum in-lane + shfl_xor(16/32)
// No __syncthreads (no cross-wave shared state).
__global__ __launch_bounds__(256) void attn_kernel(
    const unsigned short* __restrict__ qg, const unsigned short* __restrict__ kg,
    const unsigned short* __restrict__ vg,
    unsigned short* __restrict__ accE, unsigned short* __restrict__ accO)
{
    __shared__ unsigned short sP[4][32][40];   // per-wave P tile, ld=40
    const int t = threadIdx.x;
    const int lane = t & 63, wv = t >> 6;
    const int a = lane & 15, g = lane >> 4;
    int bid = blockIdx.x;
    const int qh = bid & 3; bid >>= 2;
    const int w = bid % NWIN, b = bid / NWIN;
    const int nwin = STR * w;
    const int i0 = qh*128 + wv*32;

    const unsigned short* qbase = qg + ((size_t)b*NN + nwin + i0)*8;
    const unsigned short* kbase = kg + ((size_t)b*NN + nwin)*8;
    const unsigned short* vbase = vg + (size_t)b*CC*NN + nwin;
    unsigned short* myP = &sP[wv][0][0];

    // Q B-frags (col i = nt*16+a, k=d). Zero k>=8 (g>0); K side loads garbage
    // there but garbage*0 = 0.
    bf16x8 qf[2];
    #pragma unroll
    for (int nt = 0; nt < 2; ++nt) {
        bf16x8 z = {};
        bf16x8 raw = *(const bf16x8*)(qbase + (size_t)(nt*16 + a)*8);
        qf[nt] = (g == 0) ? raw : z;
    }

    f32x4 acc[4][2] = {};
    float rsum[2] = {0.f, 0.f};

    for (int jt = 0; jt < 16; ++jt) {
        const int j0 = jt*32;
        bf16x8 kf[2];
        kf[0] = *(const bf16x8*)(kbase + (size_t)(j0 + a)*8);
        kf[1] = *(const bf16x8*)(kbase + (size_t)(j0 + 16 + a)*8);
        #pragma unroll
        for (int mt = 0; mt < 2; ++mt) {
            #pragma unroll
            for (int nt = 0; nt < 2; ++nt) {
                f32x4 z4 = {};
                f32x4 e = __builtin_amdgcn_mfma_f32_16x16x32_bf16(kf[mt], qf[nt], z4, 0, 0, 0);
                float p0 = exp2f(e[0]), p1 = exp2f(e[1]);
                float p2 = exp2f(e[2]), p3 = exp2f(e[3]);
                rsum[nt] += (p0 + p1) + (p2 + p3);
                int2 pw;
                pw.x = (int)pack_bf16(p0, p1);
                pw.y = (int)pack_bf16(p2, p3);
                *(int2*)(myP + (size_t)(nt*16 + a)*40 + mt*16 + g*4) = pw;
            }
        }
        bf16x8 pf[2];
        pf[0] = *(const bf16x8*)(myP + (size_t)(a)*40 + g*8);
        pf[1] = *(const bf16x8*)(myP + (size_t)(16 + a)*40 + g*8);
        #pragma unroll
        for (int mtc = 0; mtc < 4; ++mtc) {
            bf16x8 vf = *(const bf16x8*)(vbase + (size_t)(mtc*16 + a)*NN + j0 + g*8);
            acc[mtc][0] = __builtin_amdgcn_mfma_f32_16x16x32_bf16(vf, pf[0], acc[mtc][0], 0, 0, 0);
            acc[mtc][1] = __builtin_amdgcn_mfma_f32_16x16x32_bf16(vf, pf[1], acc[mtc][1], 0, 0, 0);
        }
    }

    // normalize + store (parity-disjoint, no atomics)
    unsigned short* ob = ((w & 1) ? accO : accE) + (size_t)b*CC*NN + nwin + i0;
    #pragma unroll
    for (int nt = 0; nt < 2; ++nt) {
        float r = rsum[nt];
        r += __shfl_xor(r, 16);
        r += __shfl_xor(r, 32);
        const float inv = 1.f / r;
        #pragma unroll
        for (int mtc = 0; mtc < 4; ++mtc) {
            #pragma unroll
            for (int u = 0; u < 4; ++u)
                ob[(size_t)(mtc*16 + g*4 + u)*NN + nt*16 + a] = to_bf16(acc[mtc][nt][u] * inv);
        }
    }
}

// ---------------- kernel 3: combine + 2:1 maxpool ----------------
__global__ __launch_bounds__(256) void final_kernel(
    const float* __restrict__ x,
    const unsigned short* __restrict__ accE, const unsigned short* __restrict__ accO,
    const float* __restrict__ gamma, float* __restrict__ out)
{
    const size_t tid = (size_t)blockIdx.x*256 + threadIdx.x;  // B*C*N/8 threads
    const size_t base = tid*8;
    const int n = (int)(base & (NN-1));
    const float g = gamma[0];

    float xv[8];
    *(float4*)&xv[0] = *(const float4*)&x[base];
    *(float4*)&xv[4] = *(const float4*)&x[base+4];
    int4 aeq = *(const int4*)&accE[base];
    const unsigned int* ae = (const unsigned int*)&aeq;

    float s[8];
    if (n >= STR && n < NN - STR) {
        int4 aoq = *(const int4*)&accO[base];
        const unsigned int* ao = (const unsigned int*)&aoq;
        #pragma unroll
        for (int u = 0; u < 4; ++u) {
            float e0 = bf2f((unsigned short)(ae[u] & 0xffff));
            float e1 = bf2f((unsigned short)(ae[u] >> 16));
            float o0 = bf2f((unsigned short)(ao[u] & 0xffff));
            float o1 = bf2f((unsigned short)(ao[u] >> 16));
            s[2*u]   = fmaf(g, (e0 + o0)*0.5f, xv[2*u]);
            s[2*u+1] = fmaf(g, (e1 + o1)*0.5f, xv[2*u+1]);
        }
    } else {
        #pragma unroll
        for (int u = 0; u < 4; ++u) {
            float e0 = bf2f((unsigned short)(ae[u] & 0xffff));
            float e1 = bf2f((unsigned short)(ae[u] >> 16));
            s[2*u]   = fmaf(g, e0, xv[2*u]);
            s[2*u+1] = fmaf(g, e1, xv[2*u+1]);
        }
    }
    float4 o = make_float4(fmaxf(s[0], s[1]), fmaxf(s[2], s[3]),
                           fmaxf(s[4], s[5]), fmaxf(s[6], s[7]));
    *(float4*)&out[tid*4] = o;
}

extern "C" void kernel_launch(void* const* d_in, const int* in_sizes, int n_in,
                              void* d_out, int out_size, void* d_ws, size_t ws_size,
                              hipStream_t stream)
{
    const float* x    = (const float*)d_in[0];
    const float* Wq   = (const float*)d_in[1];
    const float* bq   = (const float*)d_in[2];
    const float* Wk   = (const float*)d_in[3];
    const float* bk   = (const float*)d_in[4];
    const float* Wv   = (const float*)d_in[5];
    const float* bv   = (const float*)d_in[6];
    const float* gamma= (const float*)d_in[7];

    unsigned short* q    = (unsigned short*)d_ws;
    unsigned short* k    = q + (size_t)BB*NN*DD;
    unsigned short* v    = k + (size_t)BB*NN*DD;
    unsigned short* accE = v + (size_t)BB*CC*NN;
    unsigned short* accO = accE + (size_t)BB*CC*NN;
    float* out = (float*)d_out;

    qkv_kernel<<<BB*NN/256, 256, 0, stream>>>(x, Wq, bq, Wk, bk, Wv, bv, q, k, v);
    attn_kernel<<<BB*NWIN*4, 256, 0, stream>>>(q, k, v, accE, accO);
    final_kernel<<<BB*CC*NN/8/256, 256, 0, stream>>>(x, accE, accO, gamma, out);
}

// Round 5
// 120.611 us; speedup vs baseline: 1.1823x; 1.1823x over previous
//
#include <hip/hip_runtime.h>
#include <hip/hip_bf16.h>

#define BB 4
#define CC 64
#define DD 8
#define NN 32768
#define WW 512
#define STR 256
#define NWIN 127
#define LOG2E 1.4426950408889634f

typedef short bf16x8 __attribute__((ext_vector_type(8)));
typedef float f32x4 __attribute__((ext_vector_type(4)));

__device__ __forceinline__ unsigned int pack_bf16(float lo, float hi) {
    __hip_bfloat162 h = __float22bfloat162_rn(make_float2(lo, hi));  // v_cvt_pk_bf16_f32
    unsigned int r; __builtin_memcpy(&r, &h, 4);
    return r;
}
__device__ __forceinline__ unsigned short to_bf16(float f) {
    __hip_bfloat16 h = __float2bfloat16(f);
    unsigned short r; __builtin_memcpy(&r, &h, 2);
    return r;
}
__device__ __forceinline__ float bf2f(unsigned short s) {
    union { unsigned int u; float f; } v; v.u = ((unsigned int)s) << 16;
    return v.f;
}

// ---------------- kernel 1: QKV projection (fp32 in, bf16 out) ----------------
// q,k layout: [b][n][8] bf16 (16B rows -> direct MFMA frag loads)
// v layout:   [b][c][n] bf16
// Wq/bq pre-scaled by log2(e) so attention uses a bare v_exp_f32.
__global__ __launch_bounds__(256) void qkv_kernel(
    const float* __restrict__ x,
    const float* __restrict__ Wq, const float* __restrict__ bq,
    const float* __restrict__ Wk, const float* __restrict__ bk,
    const float* __restrict__ Wv, const float* __restrict__ bv,
    unsigned short* __restrict__ q, unsigned short* __restrict__ k,
    unsigned short* __restrict__ v)
{
    __shared__ float sWq[DD][CC], sWk[DD][CC], sWv[CC][CC];
    __shared__ float sb[2*DD + CC];
    const int t = threadIdx.x;
    for (int i = t; i < DD*CC; i += 256) { sWq[i>>6][i&63] = Wq[i] * LOG2E; sWk[i>>6][i&63] = Wk[i]; }
    for (int i = t; i < CC*CC; i += 256) sWv[i>>6][i&63] = Wv[i];
    if (t < DD) { sb[t] = bq[t] * LOG2E; sb[DD+t] = bk[t]; }
    if (t < CC) sb[2*DD+t] = bv[t];
    __syncthreads();

    const int gid = blockIdx.x*256 + t;
    const int b = gid >> 15;
    const int n = gid & (NN-1);
    const float* xb = x + (size_t)b*CC*NN + n;
    float xr[CC];
    #pragma unroll
    for (int c = 0; c < CC; ++c) xr[c] = xb[(size_t)c*NN];

    unsigned int pq[4], pk[4];
    #pragma unroll
    for (int d2 = 0; d2 < 4; ++d2) {
        float aq0 = sb[2*d2],   ak0 = sb[DD+2*d2];
        float aq1 = sb[2*d2+1], ak1 = sb[DD+2*d2+1];
        #pragma unroll
        for (int c = 0; c < CC; ++c) {
            aq0 = fmaf(sWq[2*d2][c],   xr[c], aq0);
            ak0 = fmaf(sWk[2*d2][c],   xr[c], ak0);
            aq1 = fmaf(sWq[2*d2+1][c], xr[c], aq1);
            ak1 = fmaf(sWk[2*d2+1][c], xr[c], ak1);
        }
        pq[d2] = pack_bf16(aq0, aq1);
        pk[d2] = pack_bf16(ak0, ak1);
    }
    *(int4*)(q + ((size_t)b*NN + n)*8) = make_int4(pq[0], pq[1], pq[2], pq[3]);
    *(int4*)(k + ((size_t)b*NN + n)*8) = make_int4(pk[0], pk[1], pk[2], pk[3]);

    unsigned short* vb = v + (size_t)b*CC*NN + n;
    for (int e = 0; e < CC; ++e) {
        float a = sb[2*DD+e];
        #pragma unroll
        for (int c = 0; c < CC; ++c) a = fmaf(sWv[e][c], xr[c], a);
        vb[(size_t)e*NN] = to_bf16(a);
    }
}

// ---------------- kernel 2: windowed attention, bf16 MFMA ----------------
// block = 4 waves; block owns (b, w, half-of-window-i = 256 rows).
// Each wave owns a 64-wide i-chunk (V reuse factor 64), loops j in 32-tiles:
//   E^T = mfma(K_frag, Q_frag)  (K-dim = d, padded 8->32; Q zeroed for k>=8)
//   P = exp2(E^T) -> cvt_pk bf16 -> per-wave double-buffered LDS tile [64i][40j]
//   acc += mfma(V_frag, P_frag); rowsum in-lane + shfl_xor(16/32)
// K-frag is prefetched 1 tile deep; no __syncthreads anywhere.
__global__ __launch_bounds__(256) void attn_kernel(
    const unsigned short* __restrict__ qg, const unsigned short* __restrict__ kg,
    const unsigned short* __restrict__ vg,
    unsigned short* __restrict__ accE, unsigned short* __restrict__ accO)
{
    __shared__ unsigned short sP[4][2][64][40];   // per-wave dbuf P tile, ld=40
    const int t = threadIdx.x;
    const int lane = t & 63, wv = t >> 6;
    const int a = lane & 15, g = lane >> 4;
    int bid = blockIdx.x;
    const int ih = bid & 1; bid >>= 1;
    const int w = bid % NWIN, b = bid / NWIN;
    const int nwin = STR * w;
    const int i0 = ih*256 + wv*64;

    const unsigned short* qbase = qg + ((size_t)b*NN + nwin + i0)*8;
    const unsigned short* kbase = kg + ((size_t)b*NN + nwin)*8;
    const unsigned short* vbase = vg + (size_t)b*CC*NN + nwin;

    // Q B-frags (col i = nt*16+a, k=d). Zero k>=8 (g>0); K side may carry
    // garbage there but garbage*0 = 0.
    bf16x8 qf[4];
    #pragma unroll
    for (int nt = 0; nt < 4; ++nt) {
        bf16x8 z = {};
        bf16x8 raw = *(const bf16x8*)(qbase + (size_t)(nt*16 + a)*8);
        qf[nt] = (g == 0) ? raw : z;
    }

    f32x4 acc[4][4] = {};
    float rsum[4] = {0.f, 0.f, 0.f, 0.f};

    // prefetch K frags for jt=0
    bf16x8 kc0 = *(const bf16x8*)(kbase + (size_t)(a)*8);
    bf16x8 kc1 = *(const bf16x8*)(kbase + (size_t)(16 + a)*8);

    for (int jt = 0; jt < 16; ++jt) {
        const int j0 = jt*32;
        unsigned short* myP = &sP[wv][jt & 1][0][0];
        // issue next tile's K loads early
        bf16x8 kn0, kn1;
        if (jt < 15) {
            kn0 = *(const bf16x8*)(kbase + (size_t)(j0 + 32 + a)*8);
            kn1 = *(const bf16x8*)(kbase + (size_t)(j0 + 48 + a)*8);
        }
        // E^T tiles -> exp2 -> pack -> LDS + rowsum
        #pragma unroll
        for (int mt = 0; mt < 2; ++mt) {
            const bf16x8 kf = mt ? kc1 : kc0;
            #pragma unroll
            for (int nt = 0; nt < 4; ++nt) {
                f32x4 z4 = {};
                f32x4 e = __builtin_amdgcn_mfma_f32_16x16x32_bf16(kf, qf[nt], z4, 0, 0, 0);
                float p0 = exp2f(e[0]), p1 = exp2f(e[1]);
                float p2 = exp2f(e[2]), p3 = exp2f(e[3]);
                rsum[nt] += (p0 + p1) + (p2 + p3);
                int2 pw;
                pw.x = (int)pack_bf16(p0, p1);
                pw.y = (int)pack_bf16(p2, p3);
                *(int2*)(myP + (size_t)(nt*16 + a)*40 + mt*16 + g*4) = pw;
            }
        }
        // PV: acc[c-tile][i-tile] += V * P   (K-dim = this tile's 32 j's)
        bf16x8 pf[4];
        #pragma unroll
        for (int nt = 0; nt < 4; ++nt)
            pf[nt] = *(const bf16x8*)(myP + (size_t)(nt*16 + a)*40 + g*8);
        #pragma unroll
        for (int mtc = 0; mtc < 4; ++mtc) {
            bf16x8 vf = *(const bf16x8*)(vbase + (size_t)(mtc*16 + a)*NN + j0 + g*8);
            #pragma unroll
            for (int nt = 0; nt < 4; ++nt)
                acc[mtc][nt] = __builtin_amdgcn_mfma_f32_16x16x32_bf16(vf, pf[nt], acc[mtc][nt], 0, 0, 0);
        }
        kc0 = kn0; kc1 = kn1;
    }

    // normalize + store (parity-disjoint, no atomics)
    unsigned short* ob = ((w & 1) ? accO : accE) + (size_t)b*CC*NN + nwin + i0;
    #pragma unroll
    for (int nt = 0; nt < 4; ++nt) {
        float r = rsum[nt];
        r += __shfl_xor(r, 16);
        r += __shfl_xor(r, 32);
        const float inv = 1.f / r;
        #pragma unroll
        for (int mtc = 0; mtc < 4; ++mtc) {
            #pragma unroll
            for (int u = 0; u < 4; ++u)
                ob[(size_t)(mtc*16 + g*4 + u)*NN + nt*16 + a] = to_bf16(acc[mtc][nt][u] * inv);
        }
    }
}

// ---------------- kernel 3: combine + 2:1 maxpool ----------------
__global__ __launch_bounds__(256) void final_kernel(
    const float* __restrict__ x,
    const unsigned short* __restrict__ accE, const unsigned short* __restrict__ accO,
    const float* __restrict__ gamma, float* __restrict__ out)
{
    const size_t tid = (size_t)blockIdx.x*256 + threadIdx.x;  // B*C*N/8 threads
    const size_t base = tid*8;
    const int n = (int)(base & (NN-1));
    const float g = gamma[0];

    float xv[8];
    *(float4*)&xv[0] = *(const float4*)&x[base];
    *(float4*)&xv[4] = *(const float4*)&x[base+4];
    int4 aeq = *(const int4*)&accE[base];
    const unsigned int* ae = (const unsigned int*)&aeq;

    float s[8];
    if (n >= STR && n < NN - STR) {
        int4 aoq = *(const int4*)&accO[base];
        const unsigned int* ao = (const unsigned int*)&aoq;
        #pragma unroll
        for (int u = 0; u < 4; ++u) {
            float e0 = bf2f((unsigned short)(ae[u] & 0xffff));
            float e1 = bf2f((unsigned short)(ae[u] >> 16));
            float o0 = bf2f((unsigned short)(ao[u] & 0xffff));
            float o1 = bf2f((unsigned short)(ao[u] >> 16));
            s[2*u]   = fmaf(g, (e0 + o0)*0.5f, xv[2*u]);
            s[2*u+1] = fmaf(g, (e1 + o1)*0.5f, xv[2*u+1]);
        }
    } else {
        #pragma unroll
        for (int u = 0; u < 4; ++u) {
            float e0 = bf2f((unsigned short)(ae[u] & 0xffff));
            float e1 = bf2f((unsigned short)(ae[u] >> 16));
            s[2*u]   = fmaf(g, e0, xv[2*u]);
            s[2*u+1] = fmaf(g, e1, xv[2*u+1]);
        }
    }
    float4 o = make_float4(fmaxf(s[0], s[1]), fmaxf(s[2], s[3]),
                           fmaxf(s[4], s[5]), fmaxf(s[6], s[7]));
    *(float4*)&out[tid*4] = o;
}

extern "C" void kernel_launch(void* const* d_in, const int* in_sizes, int n_in,
                              void* d_out, int out_size, void* d_ws, size_t ws_size,
                              hipStream_t stream)
{
    const float* x    = (const float*)d_in[0];
    const float* Wq   = (const float*)d_in[1];
    const float* bq   = (const float*)d_in[2];
    const float* Wk   = (const float*)d_in[3];
    const float* bk   = (const float*)d_in[4];
    const float* Wv   = (const float*)d_in[5];
    const float* bv   = (const float*)d_in[6];
    const float* gamma= (const float*)d_in[7];

    unsigned short* q    = (unsigned short*)d_ws;
    unsigned short* k    = q + (size_t)BB*NN*DD;
    unsigned short* v    = k + (size_t)BB*NN*DD;
    unsigned short* accE = v + (size_t)BB*CC*NN;
    unsigned short* accO = accE + (size_t)BB*CC*NN;
    float* out = (float*)d_out;

    qkv_kernel<<<BB*NN/256, 256, 0, stream>>>(x, Wq, bq, Wk, bk, Wv, bv, q, k, v);
    attn_kernel<<<BB*NWIN*2, 256, 0, stream>>>(q, k, v, accE, accO);
    final_kernel<<<BB*CC*NN/8/256, 256, 0, stream>>>(x, accE, accO, gamma, out);
}

// Round 6
// 108.142 us; speedup vs baseline: 1.3186x; 1.1153x over previous
//
#include <hip/hip_runtime.h>
#include <hip/hip_bf16.h>

#define BB 4
#define CC 64
#define DD 8
#define NN 32768
#define WW 512
#define STR 256
#define NWIN 127
#define LOG2E 1.4426950408889634f

typedef short bf16x8 __attribute__((ext_vector_type(8)));
typedef float f32x4 __attribute__((ext_vector_type(4)));

__device__ __forceinline__ unsigned int pack_bf16(float lo, float hi) {
    __hip_bfloat162 h = __float22bfloat162_rn(make_float2(lo, hi));  // v_cvt_pk_bf16_f32
    unsigned int r; __builtin_memcpy(&r, &h, 4);
    return r;
}
__device__ __forceinline__ unsigned short to_bf16(float f) {
    __hip_bfloat16 h = __float2bfloat16(f);
    unsigned short r; __builtin_memcpy(&r, &h, 2);
    return r;
}
__device__ __forceinline__ float bf2f(unsigned short s) {
    union { unsigned int u; float f; } v; v.u = ((unsigned int)s) << 16;
    return v.f;
}
// guaranteed single v_exp_f32 (exp2f() is an ocml expansion -> R5's VALU wall)
__device__ __forceinline__ float fast_exp2(float x) {
#if __has_builtin(__builtin_amdgcn_exp2f)
    return __builtin_amdgcn_exp2f(x);
#else
    float r; asm("v_exp_f32 %0, %1" : "=v"(r) : "v"(x)); return r;
#endif
}

// ---------------- kernel 1: QKV projection (fp32 in, bf16 out) ----------------
// q,k layout: [b][n][8] bf16 (16B rows -> direct MFMA frag loads)
// v layout:   [b][c][n] bf16
// Wq/bq pre-scaled by log2(e) so attention uses a bare v_exp_f32.
__global__ __launch_bounds__(256) void qkv_kernel(
    const float* __restrict__ x,
    const float* __restrict__ Wq, const float* __restrict__ bq,
    const float* __restrict__ Wk, const float* __restrict__ bk,
    const float* __restrict__ Wv, const float* __restrict__ bv,
    unsigned short* __restrict__ q, unsigned short* __restrict__ k,
    unsigned short* __restrict__ v)
{
    __shared__ float sWq[DD][CC], sWk[DD][CC], sWv[CC][CC];
    __shared__ float sb[2*DD + CC];
    const int t = threadIdx.x;
    for (int i = t; i < DD*CC; i += 256) { sWq[i>>6][i&63] = Wq[i] * LOG2E; sWk[i>>6][i&63] = Wk[i]; }
    for (int i = t; i < CC*CC; i += 256) sWv[i>>6][i&63] = Wv[i];
    if (t < DD) { sb[t] = bq[t] * LOG2E; sb[DD+t] = bk[t]; }
    if (t < CC) sb[2*DD+t] = bv[t];
    __syncthreads();

    const int gid = blockIdx.x*256 + t;
    const int b = gid >> 15;
    const int n = gid & (NN-1);
    const float* xb = x + (size_t)b*CC*NN + n;
    float xr[CC];
    #pragma unroll
    for (int c = 0; c < CC; ++c) xr[c] = xb[(size_t)c*NN];

    unsigned int pq[4], pk[4];
    #pragma unroll
    for (int d2 = 0; d2 < 4; ++d2) {
        float aq0 = sb[2*d2],   ak0 = sb[DD+2*d2];
        float aq1 = sb[2*d2+1], ak1 = sb[DD+2*d2+1];
        #pragma unroll
        for (int c = 0; c < CC; ++c) {
            aq0 = fmaf(sWq[2*d2][c],   xr[c], aq0);
            ak0 = fmaf(sWk[2*d2][c],   xr[c], ak0);
            aq1 = fmaf(sWq[2*d2+1][c], xr[c], aq1);
            ak1 = fmaf(sWk[2*d2+1][c], xr[c], ak1);
        }
        pq[d2] = pack_bf16(aq0, aq1);
        pk[d2] = pack_bf16(ak0, ak1);
    }
    *(int4*)(q + ((size_t)b*NN + n)*8) = make_int4(pq[0], pq[1], pq[2], pq[3]);
    *(int4*)(k + ((size_t)b*NN + n)*8) = make_int4(pk[0], pk[1], pk[2], pk[3]);

    unsigned short* vb = v + (size_t)b*CC*NN + n;
    for (int e = 0; e < CC; ++e) {
        float a = sb[2*DD+e];
        #pragma unroll
        for (int c = 0; c < CC; ++c) a = fmaf(sWv[e][c], xr[c], a);
        vb[(size_t)e*NN] = to_bf16(a);
    }
}

// ---------------- kernel 2: windowed attention, bf16 MFMA ----------------
// block = 4 waves; block owns (b, w, half-of-window-i = 256 rows).
// Each wave owns a 64-wide i-chunk (V reuse factor 64), loops j in 32-tiles:
//   V frags for this tile issued FIRST (latency hides under E^T/exp phase)
//   E^T = mfma(K_frag, Q_frag)  (K-dim = d, padded 8->32; Q zeroed for k>=8)
//   P = v_exp(E^T) -> cvt_pk bf16 -> per-wave LDS tile [64i][40j]
//   acc += mfma(V_frag, P_frag); rowsum in-lane + shfl_xor(16/32)
// K-frag prefetched 1 tile deep; no __syncthreads anywhere.
__global__ __launch_bounds__(256) void attn_kernel(
    const unsigned short* __restrict__ qg, const unsigned short* __restrict__ kg,
    const unsigned short* __restrict__ vg,
    unsigned short* __restrict__ accE, unsigned short* __restrict__ accO)
{
    __shared__ unsigned short sP[4][64][40];   // per-wave P tile, ld=40
    const int t = threadIdx.x;
    const int lane = t & 63, wv = t >> 6;
    const int a = lane & 15, g = lane >> 4;
    int bid = blockIdx.x;
    const int ih = bid & 1; bid >>= 1;
    const int w = bid % NWIN, b = bid / NWIN;
    const int nwin = STR * w;
    const int i0 = ih*256 + wv*64;

    const unsigned short* qbase = qg + ((size_t)b*NN + nwin + i0)*8;
    const unsigned short* kbase = kg + ((size_t)b*NN + nwin)*8;
    const unsigned short* vbase = vg + (size_t)b*CC*NN + nwin;
    unsigned short* myP = &sP[wv][0][0];

    // Q B-frags (col i = nt*16+a, k=d). Zero k>=8 (g>0); K side may carry
    // garbage there but garbage*0 = 0.
    bf16x8 qf[4];
    #pragma unroll
    for (int nt = 0; nt < 4; ++nt) {
        bf16x8 z = {};
        bf16x8 raw = *(const bf16x8*)(qbase + (size_t)(nt*16 + a)*8);
        qf[nt] = (g == 0) ? raw : z;
    }

    f32x4 acc[4][4] = {};
    float rsum[4] = {0.f, 0.f, 0.f, 0.f};

    // prefetch K frags for jt=0
    bf16x8 kc0 = *(const bf16x8*)(kbase + (size_t)(a)*8);
    bf16x8 kc1 = *(const bf16x8*)(kbase + (size_t)(16 + a)*8);

    for (int jt = 0; jt < 16; ++jt) {
        const int j0 = jt*32;
        // V frags for THIS tile: issue before E^T so latency hides under it
        bf16x8 vf[4];
        #pragma unroll
        for (int mtc = 0; mtc < 4; ++mtc)
            vf[mtc] = *(const bf16x8*)(vbase + (size_t)(mtc*16 + a)*NN + j0 + g*8);
        // next tile's K frags
        bf16x8 kn0, kn1;
        if (jt < 15) {
            kn0 = *(const bf16x8*)(kbase + (size_t)(j0 + 32 + a)*8);
            kn1 = *(const bf16x8*)(kbase + (size_t)(j0 + 48 + a)*8);
        }
        // E^T tiles -> exp -> pack -> LDS + rowsum
        #pragma unroll
        for (int mt = 0; mt < 2; ++mt) {
            const bf16x8 kf = mt ? kc1 : kc0;
            #pragma unroll
            for (int nt = 0; nt < 4; ++nt) {
                f32x4 z4 = {};
                f32x4 e = __builtin_amdgcn_mfma_f32_16x16x32_bf16(kf, qf[nt], z4, 0, 0, 0);
                float p0 = fast_exp2(e[0]), p1 = fast_exp2(e[1]);
                float p2 = fast_exp2(e[2]), p3 = fast_exp2(e[3]);
                rsum[nt] += (p0 + p1) + (p2 + p3);
                int2 pw;
                pw.x = (int)pack_bf16(p0, p1);
                pw.y = (int)pack_bf16(p2, p3);
                *(int2*)(myP + (size_t)(nt*16 + a)*40 + mt*16 + g*4) = pw;
            }
        }
        // PV: acc[c-tile][i-tile] += V * P   (K-dim = this tile's 32 j's)
        bf16x8 pf[4];
        #pragma unroll
        for (int nt = 0; nt < 4; ++nt)
            pf[nt] = *(const bf16x8*)(myP + (size_t)(nt*16 + a)*40 + g*8);
        #pragma unroll
        for (int mtc = 0; mtc < 4; ++mtc) {
            #pragma unroll
            for (int nt = 0; nt < 4; ++nt)
                acc[mtc][nt] = __builtin_amdgcn_mfma_f32_16x16x32_bf16(vf[mtc], pf[nt], acc[mtc][nt], 0, 0, 0);
        }
        kc0 = kn0; kc1 = kn1;
    }

    // normalize + store (parity-disjoint, no atomics)
    unsigned short* ob = ((w & 1) ? accO : accE) + (size_t)b*CC*NN + nwin + i0;
    #pragma unroll
    for (int nt = 0; nt < 4; ++nt) {
        float r = rsum[nt];
        r += __shfl_xor(r, 16);
        r += __shfl_xor(r, 32);
        const float inv = 1.f / r;
        #pragma unroll
        for (int mtc = 0; mtc < 4; ++mtc) {
            #pragma unroll
            for (int u = 0; u < 4; ++u)
                ob[(size_t)(mtc*16 + g*4 + u)*NN + nt*16 + a] = to_bf16(acc[mtc][nt][u] * inv);
        }
    }
}

// ---------------- kernel 3: combine + 2:1 maxpool ----------------
__global__ __launch_bounds__(256) void final_kernel(
    const float* __restrict__ x,
    const unsigned short* __restrict__ accE, const unsigned short* __restrict__ accO,
    const float* __restrict__ gamma, float* __restrict__ out)
{
    const size_t tid = (size_t)blockIdx.x*256 + threadIdx.x;  // B*C*N/8 threads
    const size_t base = tid*8;
    const int n = (int)(base & (NN-1));
    const float g = gamma[0];

    float xv[8];
    *(float4*)&xv[0] = *(const float4*)&x[base];
    *(float4*)&xv[4] = *(const float4*)&x[base+4];
    int4 aeq = *(const int4*)&accE[base];
    const unsigned int* ae = (const unsigned int*)&aeq;

    float s[8];
    if (n >= STR && n < NN - STR) {
        int4 aoq = *(const int4*)&accO[base];
        const unsigned int* ao = (const unsigned int*)&aoq;
        #pragma unroll
        for (int u = 0; u < 4; ++u) {
            float e0 = bf2f((unsigned short)(ae[u] & 0xffff));
            float e1 = bf2f((unsigned short)(ae[u] >> 16));
            float o0 = bf2f((unsigned short)(ao[u] & 0xffff));
            float o1 = bf2f((unsigned short)(ao[u] >> 16));
            s[2*u]   = fmaf(g, (e0 + o0)*0.5f, xv[2*u]);
            s[2*u+1] = fmaf(g, (e1 + o1)*0.5f, xv[2*u+1]);
        }
    } else {
        #pragma unroll
        for (int u = 0; u < 4; ++u) {
            float e0 = bf2f((unsigned short)(ae[u] & 0xffff));
            float e1 = bf2f((unsigned short)(ae[u] >> 16));
            s[2*u]   = fmaf(g, e0, xv[2*u]);
            s[2*u+1] = fmaf(g, e1, xv[2*u+1]);
        }
    }
    float4 o = make_float4(fmaxf(s[0], s[1]), fmaxf(s[2], s[3]),
                           fmaxf(s[4], s[5]), fmaxf(s[6], s[7]));
    *(float4*)&out[tid*4] = o;
}

extern "C" void kernel_launch(void* const* d_in, const int* in_sizes, int n_in,
                              void* d_out, int out_size, void* d_ws, size_t ws_size,
                              hipStream_t stream)
{
    const float* x    = (const float*)d_in[0];
    const float* Wq   = (const float*)d_in[1];
    const float* bq   = (const float*)d_in[2];
    const float* Wk   = (const float*)d_in[3];
    const float* bk   = (const float*)d_in[4];
    const float* Wv   = (const float*)d_in[5];
    const float* bv   = (const float*)d_in[6];
    const float* gamma= (const float*)d_in[7];

    unsigned short* q    = (unsigned short*)d_ws;
    unsigned short* k    = q + (size_t)BB*NN*DD;
    unsigned short* v    = k + (size_t)BB*NN*DD;
    unsigned short* accE = v + (size_t)BB*CC*NN;
    unsigned short* accO = accE + (size_t)BB*CC*NN;
    float* out = (float*)d_out;

    qkv_kernel<<<BB*NN/256, 256, 0, stream>>>(x, Wq, bq, Wk, bk, Wv, bv, q, k, v);
    attn_kernel<<<BB*NWIN*2, 256, 0, stream>>>(q, k, v, accE, accO);
    final_kernel<<<BB*CC*NN/8/256, 256, 0, stream>>>(x, accE, accO, gamma, out);
}

// Round 7
// 82.241 us; speedup vs baseline: 1.7338x; 1.3149x over previous
//
#include <hip/hip_runtime.h>
#include <hip/hip_bf16.h>

#define BB 4
#define CC 64
#define DD 8
#define NN 32768
#define WW 512
#define STR 256
#define NWIN 127
#define LOG2E 1.4426950408889634f

typedef short bf16x8 __attribute__((ext_vector_type(8)));
typedef float f32x4 __attribute__((ext_vector_type(4)));

__device__ __forceinline__ unsigned int pack_bf16(float lo, float hi) {
    __hip_bfloat162 h = __float22bfloat162_rn(make_float2(lo, hi));  // v_cvt_pk_bf16_f32
    unsigned int r; __builtin_memcpy(&r, &h, 4);
    return r;
}
__device__ __forceinline__ unsigned short to_bf16(float f) {
    __hip_bfloat16 h = __float2bfloat16(f);
    unsigned short r; __builtin_memcpy(&r, &h, 2);
    return r;
}
__device__ __forceinline__ float bf2f(unsigned short s) {
    union { unsigned int u; float f; } v; v.u = ((unsigned int)s) << 16;
    return v.f;
}
// guaranteed single v_exp_f32 (exp2f() is an ocml expansion)
__device__ __forceinline__ float fast_exp2(float x) {
#if __has_builtin(__builtin_amdgcn_exp2f)
    return __builtin_amdgcn_exp2f(x);
#else
    float r; asm("v_exp_f32 %0, %1" : "=v"(r) : "v"(x)); return r;
#endif
}
__device__ __forceinline__ bf16x8 pack8(float a0, float a1, float a2, float a3,
                                        float a4, float a5, float a6, float a7) {
    union { bf16x8 v; unsigned int u[4]; } r;
    r.u[0] = pack_bf16(a0, a1); r.u[1] = pack_bf16(a2, a3);
    r.u[2] = pack_bf16(a4, a5); r.u[3] = pack_bf16(a6, a7);
    return r.v;
}

// ---------------- kernel 1: QKV projection as MFMA GEMM ----------------
// out[80][B*N] = W80x64 . x[64][B*N], biases folded into the MFMA C-operand.
// Row tiles: T=0 -> rows 0..7 = Wq*log2e, 8..15 = Wk; T=1..4 -> Wv rows.
// Each wave owns 16 output columns per chunk; A-frags persist in registers.
// q,k out: [b][n][8] bf16 ; v out: [b][c][n] bf16.
__global__ __launch_bounds__(256) void qkv_kernel(
    const float* __restrict__ x,
    const float* __restrict__ Wq, const float* __restrict__ bq,
    const float* __restrict__ Wk, const float* __restrict__ bk,
    const float* __restrict__ Wv, const float* __restrict__ bv,
    unsigned short* __restrict__ qout, unsigned short* __restrict__ kout,
    unsigned short* __restrict__ vout)
{
    const int t = threadIdx.x;
    const int lane = t & 63, wv = t >> 6;
    const int a = lane & 15, g = lane >> 4;

    // ---- one-time: A-frags (W) + bias accumulator init ----
    bf16x8 wf[5][2];
    #pragma unroll
    for (int T = 0; T < 5; ++T) {
        const float* wrow;
        float scale = 1.f;
        if (T == 0) {
            if (a < 8) { wrow = Wq + a*CC; scale = LOG2E; }
            else       { wrow = Wk + (a-8)*CC; }
        } else {
            wrow = Wv + ((T-1)*16 + a)*CC;
        }
        #pragma unroll
        for (int h = 0; h < 2; ++h) {
            float4 w0 = *(const float4*)(wrow + h*32 + g*8);
            float4 w1 = *(const float4*)(wrow + h*32 + g*8 + 4);
            wf[T][h] = pack8(w0.x*scale, w0.y*scale, w0.z*scale, w0.w*scale,
                             w1.x*scale, w1.y*scale, w1.z*scale, w1.w*scale);
        }
    }
    f32x4 bias[5];
    {
        const int r = g*4;
        #pragma unroll
        for (int u = 0; u < 4; ++u) {
            int rr = r + u;
            bias[0][u] = (rr < 8) ? bq[rr]*LOG2E : bk[rr-8];
        }
        #pragma unroll
        for (int T = 1; T < 5; ++T)
            #pragma unroll
            for (int u = 0; u < 4; ++u)
                bias[T][u] = bv[(T-1)*16 + r + u];
    }

    // ---- grid-stride over 16-col chunks: 8192 chunks / 4096 waves = 2 ----
    const int wave_id = blockIdx.x*4 + wv;
    #pragma unroll 1
    for (int it = 0; it < 2; ++it) {
        const int chunk = wave_id + it*4096;
        const int b = chunk >> 11;              // 2048 chunks per batch
        const int n0 = (chunk & 2047) * 16;
        const int n = n0 + a;
        const float* xcol = x + (size_t)b*CC*NN + n;

        // B-frags: x[c][n], c = h*32 + g*8 + u, bf16-converted
        float xv0[8], xv1[8];
        #pragma unroll
        for (int u = 0; u < 8; ++u) xv0[u] = xcol[(size_t)(g*8 + u)*NN];
        #pragma unroll
        for (int u = 0; u < 8; ++u) xv1[u] = xcol[(size_t)(32 + g*8 + u)*NN];
        bf16x8 xb0 = pack8(xv0[0],xv0[1],xv0[2],xv0[3],xv0[4],xv0[5],xv0[6],xv0[7]);
        bf16x8 xb1 = pack8(xv1[0],xv1[1],xv1[2],xv1[3],xv1[4],xv1[5],xv1[6],xv1[7]);

        f32x4 acc[5];
        #pragma unroll
        for (int T = 0; T < 5; ++T) {
            acc[T] = __builtin_amdgcn_mfma_f32_16x16x32_bf16(wf[T][0], xb0, bias[T], 0, 0, 0);
            acc[T] = __builtin_amdgcn_mfma_f32_16x16x32_bf16(wf[T][1], xb1, acc[T], 0, 0, 0);
        }

        // epilogue: T=0 -> q/k packed 8B store; T>=1 -> v scalar stores
        {
            unsigned int lo = pack_bf16(acc[0][0], acc[0][1]);
            unsigned int hi = pack_bf16(acc[0][2], acc[0][3]);
            unsigned short* base = ((g < 2) ? qout : kout) + ((size_t)b*NN + n)*8 + (g & 1)*4;
            *(int2*)base = make_int2((int)lo, (int)hi);
        }
        #pragma unroll
        for (int T = 1; T < 5; ++T) {
            #pragma unroll
            for (int u = 0; u < 4; ++u) {
                const int e = (T-1)*16 + g*4 + u;
                vout[((size_t)b*CC + e)*NN + n] = to_bf16(acc[T][u]);
            }
        }
    }
}

// ---------------- kernel 2: windowed attention, bf16 MFMA ----------------
// block = 4 waves; block owns (b, w, half-of-window-i = 256 rows).
// Each wave owns a 64-wide i-chunk (V reuse factor 64), loops j in 32-tiles:
//   V frags for this tile issued FIRST (latency hides under E^T/exp phase)
//   E^T = mfma(K_frag, Q_frag)  (K-dim = d, padded 8->32; Q zeroed for k>=8)
//   P = v_exp(E^T) -> cvt_pk bf16 -> per-wave LDS tile [64i][40j]
//   acc += mfma(V_frag, P_frag); rowsum in-lane + shfl_xor(16/32)
// K-frag prefetched 1 tile deep; no __syncthreads anywhere.
__global__ __launch_bounds__(256) void attn_kernel(
    const unsigned short* __restrict__ qg, const unsigned short* __restrict__ kg,
    const unsigned short* __restrict__ vg,
    unsigned short* __restrict__ accE, unsigned short* __restrict__ accO)
{
    __shared__ unsigned short sP[4][64][40];   // per-wave P tile, ld=40
    const int t = threadIdx.x;
    const int lane = t & 63, wv = t >> 6;
    const int a = lane & 15, g = lane >> 4;
    int bid = blockIdx.x;
    const int ih = bid & 1; bid >>= 1;
    const int w = bid % NWIN, b = bid / NWIN;
    const int nwin = STR * w;
    const int i0 = ih*256 + wv*64;

    const unsigned short* qbase = qg + ((size_t)b*NN + nwin + i0)*8;
    const unsigned short* kbase = kg + ((size_t)b*NN + nwin)*8;
    const unsigned short* vbase = vg + (size_t)b*CC*NN + nwin;
    unsigned short* myP = &sP[wv][0][0];

    // Q B-frags (col i = nt*16+a, k=d). Zero k>=8 (g>0); K side may carry
    // garbage there but garbage*0 = 0.
    bf16x8 qf[4];
    #pragma unroll
    for (int nt = 0; nt < 4; ++nt) {
        bf16x8 z = {};
        bf16x8 raw = *(const bf16x8*)(qbase + (size_t)(nt*16 + a)*8);
        qf[nt] = (g == 0) ? raw : z;
    }

    f32x4 acc[4][4] = {};
    float rsum[4] = {0.f, 0.f, 0.f, 0.f};

    // prefetch K frags for jt=0
    bf16x8 kc0 = *(const bf16x8*)(kbase + (size_t)(a)*8);
    bf16x8 kc1 = *(const bf16x8*)(kbase + (size_t)(16 + a)*8);

    for (int jt = 0; jt < 16; ++jt) {
        const int j0 = jt*32;
        // V frags for THIS tile: issue before E^T so latency hides under it
        bf16x8 vf[4];
        #pragma unroll
        for (int mtc = 0; mtc < 4; ++mtc)
            vf[mtc] = *(const bf16x8*)(vbase + (size_t)(mtc*16 + a)*NN + j0 + g*8);
        // next tile's K frags
        bf16x8 kn0, kn1;
        if (jt < 15) {
            kn0 = *(const bf16x8*)(kbase + (size_t)(j0 + 32 + a)*8);
            kn1 = *(const bf16x8*)(kbase + (size_t)(j0 + 48 + a)*8);
        }
        // E^T tiles -> exp -> pack -> LDS + rowsum
        #pragma unroll
        for (int mt = 0; mt < 2; ++mt) {
            const bf16x8 kf = mt ? kc1 : kc0;
            #pragma unroll
            for (int nt = 0; nt < 4; ++nt) {
                f32x4 z4 = {};
                f32x4 e = __builtin_amdgcn_mfma_f32_16x16x32_bf16(kf, qf[nt], z4, 0, 0, 0);
                float p0 = fast_exp2(e[0]), p1 = fast_exp2(e[1]);
                float p2 = fast_exp2(e[2]), p3 = fast_exp2(e[3]);
                rsum[nt] += (p0 + p1) + (p2 + p3);
                int2 pw;
                pw.x = (int)pack_bf16(p0, p1);
                pw.y = (int)pack_bf16(p2, p3);
                *(int2*)(myP + (size_t)(nt*16 + a)*40 + mt*16 + g*4) = pw;
            }
        }
        // PV: acc[c-tile][i-tile] += V * P   (K-dim = this tile's 32 j's)
        bf16x8 pf[4];
        #pragma unroll
        for (int nt = 0; nt < 4; ++nt)
            pf[nt] = *(const bf16x8*)(myP + (size_t)(nt*16 + a)*40 + g*8);
        #pragma unroll
        for (int mtc = 0; mtc < 4; ++mtc) {
            #pragma unroll
            for (int nt = 0; nt < 4; ++nt)
                acc[mtc][nt] = __builtin_amdgcn_mfma_f32_16x16x32_bf16(vf[mtc], pf[nt], acc[mtc][nt], 0, 0, 0);
        }
        kc0 = kn0; kc1 = kn1;
    }

    // normalize + store (parity-disjoint, no atomics)
    unsigned short* ob = ((w & 1) ? accO : accE) + (size_t)b*CC*NN + nwin + i0;
    #pragma unroll
    for (int nt = 0; nt < 4; ++nt) {
        float r = rsum[nt];
        r += __shfl_xor(r, 16);
        r += __shfl_xor(r, 32);
        const float inv = 1.f / r;
        #pragma unroll
        for (int mtc = 0; mtc < 4; ++mtc) {
            #pragma unroll
            for (int u = 0; u < 4; ++u)
                ob[(size_t)(mtc*16 + g*4 + u)*NN + nt*16 + a] = to_bf16(acc[mtc][nt][u] * inv);
        }
    }
}

// ---------------- kernel 3: combine + 2:1 maxpool ----------------
__global__ __launch_bounds__(256) void final_kernel(
    const float* __restrict__ x,
    const unsigned short* __restrict__ accE, const unsigned short* __restrict__ accO,
    const float* __restrict__ gamma, float* __restrict__ out)
{
    const size_t tid = (size_t)blockIdx.x*256 + threadIdx.x;  // B*C*N/8 threads
    const size_t base = tid*8;
    const int n = (int)(base & (NN-1));
    const float g = gamma[0];

    float xv[8];
    *(float4*)&xv[0] = *(const float4*)&x[base];
    *(float4*)&xv[4] = *(const float4*)&x[base+4];
    int4 aeq = *(const int4*)&accE[base];
    const unsigned int* ae = (const unsigned int*)&aeq;

    float s[8];
    if (n >= STR && n < NN - STR) {
        int4 aoq = *(const int4*)&accO[base];
        const unsigned int* ao = (const unsigned int*)&aoq;
        #pragma unroll
        for (int u = 0; u < 4; ++u) {
            float e0 = bf2f((unsigned short)(ae[u] & 0xffff));
            float e1 = bf2f((unsigned short)(ae[u] >> 16));
            float o0 = bf2f((unsigned short)(ao[u] & 0xffff));
            float o1 = bf2f((unsigned short)(ao[u] >> 16));
            s[2*u]   = fmaf(g, (e0 + o0)*0.5f, xv[2*u]);
            s[2*u+1] = fmaf(g, (e1 + o1)*0.5f, xv[2*u+1]);
        }
    } else {
        #pragma unroll
        for (int u = 0; u < 4; ++u) {
            float e0 = bf2f((unsigned short)(ae[u] & 0xffff));
            float e1 = bf2f((unsigned short)(ae[u] >> 16));
            s[2*u]   = fmaf(g, e0, xv[2*u]);
            s[2*u+1] = fmaf(g, e1, xv[2*u+1]);
        }
    }
    float4 o = make_float4(fmaxf(s[0], s[1]), fmaxf(s[2], s[3]),
                           fmaxf(s[4], s[5]), fmaxf(s[6], s[7]));
    *(float4*)&out[tid*4] = o;
}

extern "C" void kernel_launch(void* const* d_in, const int* in_sizes, int n_in,
                              void* d_out, int out_size, void* d_ws, size_t ws_size,
                              hipStream_t stream)
{
    const float* x    = (const float*)d_in[0];
    const float* Wq   = (const float*)d_in[1];
    const float* bq   = (const float*)d_in[2];
    const float* Wk   = (const float*)d_in[3];
    const float* bk   = (const float*)d_in[4];
    const float* Wv   = (const float*)d_in[5];
    const float* bv   = (const float*)d_in[6];
    const float* gamma= (const float*)d_in[7];

    unsigned short* q    = (unsigned short*)d_ws;
    unsigned short* k    = q + (size_t)BB*NN*DD;
    unsigned short* v    = k + (size_t)BB*NN*DD;
    unsigned short* accE = v + (size_t)BB*CC*NN;
    unsigned short* accO = accE + (size_t)BB*CC*NN;
    float* out = (float*)d_out;

    qkv_kernel<<<1024, 256, 0, stream>>>(x, Wq, bq, Wk, bk, Wv, bv, q, k, v);
    attn_kernel<<<BB*NWIN*2, 256, 0, stream>>>(q, k, v, accE, accO);
    final_kernel<<<BB*CC*NN/8/256, 256, 0, stream>>>(x, accE, accO, gamma, out);
}

// Round 8
// 79.529 us; speedup vs baseline: 1.7930x; 1.0341x over previous
//
#include <hip/hip_runtime.h>
#include <hip/hip_bf16.h>

#define BB 4
#define CC 64
#define DD 8
#define NN 32768
#define WW 512
#define STR 256
#define NWIN 127
#define LOG2E 1.4426950408889634f

typedef short bf16x8 __attribute__((ext_vector_type(8)));
typedef float f32x4 __attribute__((ext_vector_type(4)));
typedef float f32x16 __attribute__((ext_vector_type(16)));

__device__ __forceinline__ unsigned int pack_bf16(float lo, float hi) {
    __hip_bfloat162 h = __float22bfloat162_rn(make_float2(lo, hi));  // v_cvt_pk_bf16_f32
    unsigned int r; __builtin_memcpy(&r, &h, 4);
    return r;
}
__device__ __forceinline__ unsigned short to_bf16(float f) {
    __hip_bfloat16 h = __float2bfloat16(f);
    unsigned short r; __builtin_memcpy(&r, &h, 2);
    return r;
}
__device__ __forceinline__ float bf2f(unsigned short s) {
    union { unsigned int u; float f; } v; v.u = ((unsigned int)s) << 16;
    return v.f;
}
// guaranteed single v_exp_f32 (exp2f() is an ocml expansion)
__device__ __forceinline__ float fast_exp2(float x) {
#if __has_builtin(__builtin_amdgcn_exp2f)
    return __builtin_amdgcn_exp2f(x);
#else
    float r; asm("v_exp_f32 %0, %1" : "=v"(r) : "v"(x)); return r;
#endif
}
// swap upper 32 lanes of x with lower 32 lanes of y (gfx950)
__device__ __forceinline__ void plswap(unsigned int &x, unsigned int &y) {
    asm("v_permlane32_swap_b32 %0, %1" : "+v"(x), "+v"(y));
}
__device__ __forceinline__ bf16x8 pack8(float a0, float a1, float a2, float a3,
                                        float a4, float a5, float a6, float a7) {
    union { bf16x8 v; unsigned int u[4]; } r;
    r.u[0] = pack_bf16(a0, a1); r.u[1] = pack_bf16(a2, a3);
    r.u[2] = pack_bf16(a4, a5); r.u[3] = pack_bf16(a6, a7);
    return r.v;
}
__device__ __forceinline__ bf16x8 words4(unsigned int w0, unsigned int w1,
                                         unsigned int w2, unsigned int w3) {
    union { bf16x8 v; unsigned int u[4]; } r;
    r.u[0] = w0; r.u[1] = w1; r.u[2] = w2; r.u[3] = w3;
    return r.v;
}

// ---------------- kernel 1: QKV projection as MFMA GEMM ----------------
__global__ __launch_bounds__(256) void qkv_kernel(
    const float* __restrict__ x,
    const float* __restrict__ Wq, const float* __restrict__ bq,
    const float* __restrict__ Wk, const float* __restrict__ bk,
    const float* __restrict__ Wv, const float* __restrict__ bv,
    unsigned short* __restrict__ qout, unsigned short* __restrict__ kout,
    unsigned short* __restrict__ vout)
{
    const int t = threadIdx.x;
    const int lane = t & 63, wv = t >> 6;
    const int a = lane & 15, g = lane >> 4;

    bf16x8 wf[5][2];
    #pragma unroll
    for (int T = 0; T < 5; ++T) {
        const float* wrow;
        float scale = 1.f;
        if (T == 0) {
            if (a < 8) { wrow = Wq + a*CC; scale = LOG2E; }
            else       { wrow = Wk + (a-8)*CC; }
        } else {
            wrow = Wv + ((T-1)*16 + a)*CC;
        }
        #pragma unroll
        for (int h = 0; h < 2; ++h) {
            float4 w0 = *(const float4*)(wrow + h*32 + g*8);
            float4 w1 = *(const float4*)(wrow + h*32 + g*8 + 4);
            wf[T][h] = pack8(w0.x*scale, w0.y*scale, w0.z*scale, w0.w*scale,
                             w1.x*scale, w1.y*scale, w1.z*scale, w1.w*scale);
        }
    }
    f32x4 bias[5];
    {
        const int r = g*4;
        #pragma unroll
        for (int u = 0; u < 4; ++u) {
            int rr = r + u;
            bias[0][u] = (rr < 8) ? bq[rr]*LOG2E : bk[rr-8];
        }
        #pragma unroll
        for (int T = 1; T < 5; ++T)
            #pragma unroll
            for (int u = 0; u < 4; ++u)
                bias[T][u] = bv[(T-1)*16 + r + u];
    }

    const int wave_id = blockIdx.x*4 + wv;
    #pragma unroll 1
    for (int it = 0; it < 2; ++it) {
        const int chunk = wave_id + it*4096;
        const int b = chunk >> 11;
        const int n0 = (chunk & 2047) * 16;
        const int n = n0 + a;
        const float* xcol = x + (size_t)b*CC*NN + n;

        float xv0[8], xv1[8];
        #pragma unroll
        for (int u = 0; u < 8; ++u) xv0[u] = xcol[(size_t)(g*8 + u)*NN];
        #pragma unroll
        for (int u = 0; u < 8; ++u) xv1[u] = xcol[(size_t)(32 + g*8 + u)*NN];
        bf16x8 xb0 = pack8(xv0[0],xv0[1],xv0[2],xv0[3],xv0[4],xv0[5],xv0[6],xv0[7]);
        bf16x8 xb1 = pack8(xv1[0],xv1[1],xv1[2],xv1[3],xv1[4],xv1[5],xv1[6],xv1[7]);

        f32x4 acc[5];
        #pragma unroll
        for (int T = 0; T < 5; ++T) {
            acc[T] = __builtin_amdgcn_mfma_f32_16x16x32_bf16(wf[T][0], xb0, bias[T], 0, 0, 0);
            acc[T] = __builtin_amdgcn_mfma_f32_16x16x32_bf16(wf[T][1], xb1, acc[T], 0, 0, 0);
        }

        {
            unsigned int lo = pack_bf16(acc[0][0], acc[0][1]);
            unsigned int hi = pack_bf16(acc[0][2], acc[0][3]);
            unsigned short* base = ((g < 2) ? qout : kout) + ((size_t)b*NN + n)*8 + (g & 1)*4;
            *(int2*)base = make_int2((int)lo, (int)hi);
        }
        #pragma unroll
        for (int T = 1; T < 5; ++T) {
            #pragma unroll
            for (int u = 0; u < 4; ++u) {
                const int e = (T-1)*16 + g*4 + u;
                vout[((size_t)b*CC + e)*NN + n] = to_bf16(acc[T][u]);
            }
        }
    }
}

// ---------------- kernel 2: windowed attention, 32x32x16 MFMA, no P-LDS ----------------
// block = 4 waves; block owns (b, w, half-of-window-i = 256 rows); wave owns 64 i.
// Per 32-j tile:
//   E = mfma_32x32x16(K_j32, Q_i32)   (lane: col i=lane&31, row j=(r&3)+8(r>>2)+4*hi)
//   p = v_exp(E); pack pairs -> 8 words; v_permlane32_swap builds the PV A-frag
//   (k=8*hi+e) IN REGISTER -- zero LDS traffic for P.
//   acc[it][ct] += mfma_32x32x16(P_frag, V^T_frag)
// Normalization: rsum per-lane (i=lane&31) + shfl_xor(32); 1KB LDS broadcast of 1/r.
__global__ __launch_bounds__(256) void attn_kernel(
    const unsigned short* __restrict__ qg, const unsigned short* __restrict__ kg,
    const unsigned short* __restrict__ vg,
    unsigned short* __restrict__ accE, unsigned short* __restrict__ accO)
{
    __shared__ float sInv[4][2][32];
    const int t = threadIdx.x;
    const int lane = t & 63, wv = t >> 6;
    const int l31 = lane & 31, hi = lane >> 5;
    int bid = blockIdx.x;
    const int ih = bid & 1; bid >>= 1;
    const int w = bid % NWIN, b = bid / NWIN;
    const int nwin = STR * w;
    const int i0 = ih*256 + wv*64;

    const unsigned short* qbase = qg + ((size_t)b*NN + nwin + i0)*8;
    const unsigned short* kbase = kg + ((size_t)b*NN + nwin)*8;
    const unsigned short* vbase = vg + (size_t)b*CC*NN + nwin;

    const bf16x8 zf = {};
    // Q B-frags: col i = l31 (+32*it), k = d = 8*hi+e; hi half zeroed (d pad)
    bf16x8 qf[2];
    #pragma unroll
    for (int it = 0; it < 2; ++it) {
        bf16x8 raw = *(const bf16x8*)(qbase + (size_t)(it*32 + l31)*8);
        qf[it] = hi ? zf : raw;
    }
    // K A-frag for jt=0: row j = l31, k = d
    bf16x8 kc;
    {
        bf16x8 raw = *(const bf16x8*)(kbase + (size_t)l31*8);
        kc = hi ? zf : raw;
    }

    f32x16 acc[2][2] = {};    // [it][ct]
    float rsum[2] = {0.f, 0.f};

    for (int jt = 0; jt < 16; ++jt) {
        const int j0 = jt*32;
        // V^T B-frags: col c = ct*32+l31, k = j = 8*hi+e (+16*slab)
        bf16x8 vf[2][2];
        #pragma unroll
        for (int ct = 0; ct < 2; ++ct)
            #pragma unroll
            for (int sl = 0; sl < 2; ++sl)
                vf[ct][sl] = *(const bf16x8*)(vbase + (size_t)(ct*32 + l31)*NN + j0 + sl*16 + hi*8);
        // prefetch next K
        bf16x8 kn = kc;
        if (jt < 15) {
            bf16x8 raw = *(const bf16x8*)(kbase + (size_t)(j0 + 32 + l31)*8);
            kn = hi ? zf : raw;
        }

        #pragma unroll
        for (int it = 0; it < 2; ++it) {
            const f32x16 z16 = {};
            f32x16 E = __builtin_amdgcn_mfma_f32_32x32x16_bf16(kc, qf[it], z16, 0, 0, 0);
            float p[16];
            #pragma unroll
            for (int r = 0; r < 16; ++r) p[r] = fast_exp2(E[r]);
            // rowsum (tree)
            float s01 = (p[0]+p[1]) + (p[2]+p[3]);
            float s23 = (p[4]+p[5]) + (p[6]+p[7]);
            float s45 = (p[8]+p[9]) + (p[10]+p[11]);
            float s67 = (p[12]+p[13]) + (p[14]+p[15]);
            rsum[it] += (s01+s23) + (s45+s67);
            // pack to words: wd[tw] = (p[2tw], p[2tw+1]) -> j = {2tw,2tw+1} pattern
            unsigned int wd[8];
            #pragma unroll
            for (int tw = 0; tw < 8; ++tw) wd[tw] = pack_bf16(p[2*tw], p[2*tw+1]);
            // build PV A-frags via permlane32_swap (resolves the 4*hi row split)
            unsigned int F0 = wd[0], F2 = wd[2]; plswap(F0, F2);
            unsigned int F1 = wd[1], F3 = wd[3]; plswap(F1, F3);
            unsigned int G0 = wd[4], G2 = wd[6]; plswap(G0, G2);
            unsigned int G1 = wd[5], G3 = wd[7]; plswap(G1, G3);
            bf16x8 pa0 = words4(F0, F1, F2, F3);   // k-slab j0+0..15
            bf16x8 pa1 = words4(G0, G1, G2, G3);   // k-slab j0+16..31
            #pragma unroll
            for (int ct = 0; ct < 2; ++ct) {
                acc[it][ct] = __builtin_amdgcn_mfma_f32_32x32x16_bf16(pa0, vf[ct][0], acc[it][ct], 0, 0, 0);
                acc[it][ct] = __builtin_amdgcn_mfma_f32_32x32x16_bf16(pa1, vf[ct][1], acc[it][ct], 0, 0, 0);
            }
        }
        kc = kn;
    }

    // ---- normalization: combine hi/lo j-halves, broadcast 1/r via 1KB LDS ----
    #pragma unroll
    for (int it = 0; it < 2; ++it) rsum[it] += __shfl_xor(rsum[it], 32);
    if (lane < 32) {
        sInv[wv][0][lane] = 1.f / rsum[0];
        sInv[wv][1][lane] = 1.f / rsum[1];
    }
    f32x4 invv[2][4];
    #pragma unroll
    for (int it = 0; it < 2; ++it)
        #pragma unroll
        for (int g = 0; g < 4; ++g)
            invv[it][g] = *(const f32x4*)&sInv[wv][it][8*g + 4*hi];

    unsigned short* ob = ((w & 1) ? accO : accE) + (size_t)b*CC*NN + nwin + i0;
    #pragma unroll
    for (int it = 0; it < 2; ++it) {
        #pragma unroll
        for (int ct = 0; ct < 2; ++ct) {
            unsigned short* cbase = ob + (size_t)(ct*32 + l31)*NN + it*32;
            #pragma unroll
            for (int g = 0; g < 4; ++g) {
                float a0 = acc[it][ct][4*g+0] * invv[it][g][0];
                float a1 = acc[it][ct][4*g+1] * invv[it][g][1];
                float a2 = acc[it][ct][4*g+2] * invv[it][g][2];
                float a3 = acc[it][ct][4*g+3] * invv[it][g][3];
                int2 pw = make_int2((int)pack_bf16(a0, a1), (int)pack_bf16(a2, a3));
                *(int2*)(cbase + 8*g + 4*hi) = pw;
            }
        }
    }
}

// ---------------- kernel 3: combine + 2:1 maxpool ----------------
__global__ __launch_bounds__(256) void final_kernel(
    const float* __restrict__ x,
    const unsigned short* __restrict__ accE, const unsigned short* __restrict__ accO,
    const float* __restrict__ gamma, float* __restrict__ out)
{
    const size_t tid = (size_t)blockIdx.x*256 + threadIdx.x;  // B*C*N/8 threads
    const size_t base = tid*8;
    const int n = (int)(base & (NN-1));
    const float g = gamma[0];

    float xv[8];
    *(float4*)&xv[0] = *(const float4*)&x[base];
    *(float4*)&xv[4] = *(const float4*)&x[base+4];
    int4 aeq = *(const int4*)&accE[base];
    const unsigned int* ae = (const unsigned int*)&aeq;

    float s[8];
    if (n >= STR && n < NN - STR) {
        int4 aoq = *(const int4*)&accO[base];
        const unsigned int* ao = (const unsigned int*)&aoq;
        #pragma unroll
        for (int u = 0; u < 4; ++u) {
            float e0 = bf2f((unsigned short)(ae[u] & 0xffff));
            float e1 = bf2f((unsigned short)(ae[u] >> 16));
            float o0 = bf2f((unsigned short)(ao[u] & 0xffff));
            float o1 = bf2f((unsigned short)(ao[u] >> 16));
            s[2*u]   = fmaf(g, (e0 + o0)*0.5f, xv[2*u]);
            s[2*u+1] = fmaf(g, (e1 + o1)*0.5f, xv[2*u+1]);
        }
    } else {
        #pragma unroll
        for (int u = 0; u < 4; ++u) {
            float e0 = bf2f((unsigned short)(ae[u] & 0xffff));
            float e1 = bf2f((unsigned short)(ae[u] >> 16));
            s[2*u]   = fmaf(g, e0, xv[2*u]);
            s[2*u+1] = fmaf(g, e1, xv[2*u+1]);
        }
    }
    float4 o = make_float4(fmaxf(s[0], s[1]), fmaxf(s[2], s[3]),
                           fmaxf(s[4], s[5]), fmaxf(s[6], s[7]));
    *(float4*)&out[tid*4] = o;
}

extern "C" void kernel_launch(void* const* d_in, const int* in_sizes, int n_in,
                              void* d_out, int out_size, void* d_ws, size_t ws_size,
                              hipStream_t stream)
{
    const float* x    = (const float*)d_in[0];
    const float* Wq   = (const float*)d_in[1];
    const float* bq   = (const float*)d_in[2];
    const float* Wk   = (const float*)d_in[3];
    const float* bk   = (const float*)d_in[4];
    const float* Wv   = (const float*)d_in[5];
    const float* bv   = (const float*)d_in[6];
    const float* gamma= (const float*)d_in[7];

    unsigned short* q    = (unsigned short*)d_ws;
    unsigned short* k    = q + (size_t)BB*NN*DD;
    unsigned short* v    = k + (size_t)BB*NN*DD;
    unsigned short* accE = v + (size_t)BB*CC*NN;
    unsigned short* accO = accE + (size_t)BB*CC*NN;
    float* out = (float*)d_out;

    qkv_kernel<<<1024, 256, 0, stream>>>(x, Wq, bq, Wk, bk, Wv, bv, q, k, v);
    attn_kernel<<<BB*NWIN*2, 256, 0, stream>>>(q, k, v, accE, accO);
    final_kernel<<<BB*CC*NN/8/256, 256, 0, stream>>>(x, accE, accO, gamma, out);
}